// Round 16
// baseline (208.198 us; speedup 1.0000x reference)
//
#include <hip/hip_runtime.h>
#include <cstddef>

// ---------------------------------------------------------------------------
// GCN forward: 3 x ( h@W bf16 MFMA -> packed-bf16 xw -> CSR segsum+LN(+ReLU) )
// N=50000, E=800000, D: 128 -> 128 -> 128 -> 64.
// R16 = R15 with the OOB fix: feat tile stride is 2048 floats (16 rows x 128),
// not 8192 (R15 read ~76MB past feat -> HSA abort). All else identical:
//  (1) feat -> frag-ordered bf16 via LDS transpose (all gemms pure-frag),
//  (2) cvt_feat+cvt_w merged into one dispatch,
//  (3) nt-stores for agg outputs (read-once streams).
// ---------------------------------------------------------------------------

typedef __attribute__((ext_vector_type(8))) short bf16x8;
typedef __attribute__((ext_vector_type(4))) float floatx4;
typedef __attribute__((ext_vector_type(4))) unsigned int uintx4;
typedef __attribute__((ext_vector_type(2))) unsigned int uintx2;

static __device__ __forceinline__ unsigned int f2bf(float f) {
    union { float f; unsigned int u; } v; v.f = f;
    unsigned int u = v.u;
    u += 0x7fffu + ((u >> 16) & 1u);
    return u >> 16;
}
static __device__ __forceinline__ float bf_lo(unsigned int p) {
    union { unsigned int u; float f; } v; v.u = p << 16; return v.f;
}
static __device__ __forceinline__ float bf_hi(unsigned int p) {
    union { unsigned int u; float f; } v; v.u = p & 0xffff0000u; return v.f;
}
static __device__ __forceinline__ void acc8(float* a, uintx4 v) {
    a[0] += bf_lo(v.x); a[1] += bf_hi(v.x);
    a[2] += bf_lo(v.y); a[3] += bf_hi(v.y);
    a[4] += bf_lo(v.z); a[5] += bf_hi(v.z);
    a[6] += bf_lo(v.w); a[7] += bf_hi(v.w);
}
static __device__ __forceinline__ void acc4(float* a, uintx2 v) {
    a[0] += bf_lo(v.x); a[1] += bf_hi(v.x);
    a[2] += bf_lo(v.y); a[3] += bf_hi(v.y);
}

// ---- one-shot convert: feat -> frag-ordered fb, W0..2 -> frag-ordered WtF --
// blocks [0, nTiles): feat tile transpose via LDS (16 rows x 128 floats).
// blocks [nTiles, nTiles+48): W conversion (R13 cvt_w body).
__global__ __launch_bounds__(256) void cvt_all(const float* __restrict__ feat,
                                               const float* __restrict__ W0,
                                               const float* __restrict__ W1,
                                               const float* __restrict__ W2,
                                               unsigned int* __restrict__ fb,
                                               unsigned int* __restrict__ WtF,
                                               int nTiles) {
    const int b = blockIdx.x;
    if (b < nTiles) {
        __shared__ unsigned int lds[16 * 65];      // stride 65: conflict-free
        const float* src = feat + (size_t)b * 2048;   // 16 rows x 128 floats
        const int i = threadIdx.x;
        // coalesced read: thread i -> floats 8i..8i+7 (within one row; 128|8)
        float4 fa = *(const float4*)(src + i * 8);
        float4 fv = *(const float4*)(src + i * 8 + 4);
        const int row = i >> 4;                    // 0..15
        const int kk  = (i & 15) * 4;              // uint offset in row
        unsigned int* l = &lds[row * 65 + kk];
        l[0] = (f2bf(fa.y) << 16) | f2bf(fa.x);
        l[1] = (f2bf(fa.w) << 16) | f2bf(fa.z);
        l[2] = (f2bf(fv.y) << 16) | f2bf(fv.x);
        l[3] = (f2bf(fv.w) << 16) | f2bf(fv.z);
        __syncthreads();
        // frag-ordered write: out uint idx = b*1024 + s*256 + lane*4 + j
        const int lane = i & 63, s = i >> 6;
        const int m = lane & 15, quad = lane >> 4;
        const unsigned int* r = &lds[m * 65 + s * 16 + quad * 4];
        uintx4 v; v.x = r[0]; v.y = r[1]; v.z = r[2]; v.w = r[3];
        *(uintx4*)(fb + (size_t)b * 1024 + i * 4) = v;
    } else {
        const int wb = b - nTiles;
        const int mm = wb >> 4;
        const int slice = wb & 15;
        const float* W = (mm == 0) ? W0 : (mm == 1) ? W1 : W2;
        const int ncols = (mm == 2) ? 64 : 128;
        unsigned int* dst = WtF + mm * 128 * 64;
        const int total = ncols * 64;
        for (int idx = slice * 256 + threadIdx.x; idx < total; idx += 16 * 256) {
            const int j    = idx & 3;
            const int lane = (idx >> 2) & 63;
            const int s    = (idx >> 8) & 3;
            const int t    = idx >> 10;
            const int mcol = lane & 15;
            const int quad = lane >> 4;
            const int n = t * 16 + mcol;
            const int k = s * 32 + quad * 8 + 2 * j;
            unsigned int lo = f2bf(W[(size_t)k * ncols + n]);
            unsigned int hi = f2bf(W[(size_t)(k + 1) * ncols + n]);
            dst[idx] = (hi << 16) | lo;
        }
    }
}

// ---- bf16 MFMA GEMM, 1 wave per block, all operands fragment-ordered -------
template <int NCOLS>
__global__ __launch_bounds__(64) void gemm_mfma(const unsigned int* __restrict__ A,
                                                const unsigned int* __restrict__ Wt,
                                                unsigned int* __restrict__ C,
                                                int M) {
    const int lane = threadIdx.x;
    const int row0 = blockIdx.x * 16;
    const int quad = lane >> 4;
    const int mcol = lane & 15;

    constexpr int NT = NCOLS / 16;
    floatx4 acc[NT];
    #pragma unroll
    for (int t = 0; t < NT; ++t) acc[t] = (floatx4){0.f, 0.f, 0.f, 0.f};

    const unsigned int* afrag = A + (size_t)blockIdx.x * 1024 + lane * 4;
    const unsigned int* bbase = Wt + lane * 4;

    #pragma unroll
    for (int s = 0; s < 4; ++s) {
        uintx4 ap = *(const uintx4*)(afrag + s * 256);
        bf16x8 a = __builtin_bit_cast(bf16x8, ap);
        #pragma unroll
        for (int t = 0; t < NT; ++t) {
            uintx4 bp = *(const uintx4*)(bbase + t * 1024 + s * 256);
            bf16x8 b = __builtin_bit_cast(bf16x8, bp);
            acc[t] = __builtin_amdgcn_mfma_f32_16x16x32_bf16(a, b, acc[t], 0, 0, 0);
        }
    }

    // C/D layout: col = lane&15, row = quad*4 + reg  [m89/m91]; row-major out.
    const int rowStride = NCOLS >> 1;
    #pragma unroll
    for (int t = 0; t < NT; ++t) {
        #pragma unroll
        for (int r = 0; r < 4; ++r) {
            unsigned int mybf = f2bf(acc[t][r]);
            unsigned int pair = __shfl_xor(mybf, 1, 64);
            int orow = row0 + quad * 4 + r;
            if (orow < M && (mcol & 1) == 0) {
                unsigned int packed = (pair << 16) | mybf;
                C[(size_t)orow * rowStride + t * 8 + (mcol >> 1)] = packed;
            }
        }
    }
}

// ---- fused CSR segsum + LN + ReLU, D=128, frag-ordered bf16 out ------------
__global__ __launch_bounds__(256) void agg_ln128(const unsigned int* __restrict__ xw,
                                                 const int* __restrict__ ptr,
                                                 const int* __restrict__ col,
                                                 unsigned int* __restrict__ out,
                                                 int N) {
    const int node = blockIdx.x * 4 + (threadIdx.x >> 6);
    if (node >= N) return;
    const int lane = threadIdx.x & 63;
    const int g  = lane >> 4;     // 0..3 edge group
    const int sl = lane & 15;     // 0..15 sublane (owns 8 features)
    const int s = ptr[node];
    const int e = ptr[node + 1];

    float accA[8] = {}, accB[8] = {};
    const unsigned int* base = xw + sl * 4;
    int i = s + g;
    for (; i + 12 < e; i += 16) {
        uintx4 v0 = *(const uintx4*)(base + (size_t)col[i]      * 64);
        uintx4 v1 = *(const uintx4*)(base + (size_t)col[i + 4]  * 64);
        uintx4 v2 = *(const uintx4*)(base + (size_t)col[i + 8]  * 64);
        uintx4 v3 = *(const uintx4*)(base + (size_t)col[i + 12] * 64);
        acc8(accA, v0); acc8(accB, v1); acc8(accA, v2); acc8(accB, v3);
    }
    for (; i < e; i += 4) {
        uintx4 v0 = *(const uintx4*)(base + (size_t)col[i] * 64);
        acc8(accA, v0);
    }

    float acc[8];
    #pragma unroll
    for (int j = 0; j < 8; ++j) acc[j] = accA[j] + accB[j];

    #pragma unroll
    for (int j = 0; j < 8; ++j) {
        acc[j] += __shfl_xor(acc[j], 16, 64);
        acc[j] += __shfl_xor(acc[j], 32, 64);
    }
    float s1 = 0.f, s2 = 0.f;
    #pragma unroll
    for (int j = 0; j < 8; ++j) { s1 += acc[j]; s2 += acc[j] * acc[j]; }
    #pragma unroll
    for (int m = 8; m >= 1; m >>= 1) {
        s1 += __shfl_xor(s1, m, 64);
        s2 += __shfl_xor(s2, m, 64);
    }
    const float mean = s1 * (1.0f / 128.0f);
    const float var  = s2 * (1.0f / 128.0f) - mean * mean;
    const float inv  = rsqrtf(var + 1e-5f);

    if (g == 0) {
        float o[8];
        #pragma unroll
        for (int j = 0; j < 8; ++j)
            o[j] = fmaxf((acc[j] - mean) * inv, 0.f);
        uintx4 p;
        p.x = (f2bf(o[1]) << 16) | f2bf(o[0]);
        p.y = (f2bf(o[3]) << 16) | f2bf(o[2]);
        p.z = (f2bf(o[5]) << 16) | f2bf(o[4]);
        p.w = (f2bf(o[7]) << 16) | f2bf(o[6]);
        const int tile = node >> 4, m = node & 15;
        // hb is a read-once stream for the next gemm: bypass caches.
        __builtin_nontemporal_store(
            p, (uintx4*)(out + (size_t)tile * 1024 + (sl >> 2) * 256 + (sl & 3) * 64 + m * 4));
    }
}

// ---- fused CSR segsum + LN, D=64, fp32 out, no ReLU (final layer) ----------
__global__ __launch_bounds__(256) void agg_ln64(const unsigned int* __restrict__ xw,
                                                const int* __restrict__ ptr,
                                                const int* __restrict__ col,
                                                float* __restrict__ out, int N) {
    const int node = blockIdx.x * 4 + (threadIdx.x >> 6);
    if (node >= N) return;
    const int lane = threadIdx.x & 63;
    const int g  = lane >> 4;     // 0..3 edge group
    const int sl = lane & 15;     // 0..15 sublane (owns 4 features)
    const int s = ptr[node];
    const int e = ptr[node + 1];

    float accA[4] = {}, accB[4] = {};
    const unsigned int* base = xw + sl * 2;
    int i = s + g;
    for (; i + 12 < e; i += 16) {
        uintx2 v0 = *(const uintx2*)(base + (size_t)col[i]      * 32);
        uintx2 v1 = *(const uintx2*)(base + (size_t)col[i + 4]  * 32);
        uintx2 v2 = *(const uintx2*)(base + (size_t)col[i + 8]  * 32);
        uintx2 v3 = *(const uintx2*)(base + (size_t)col[i + 12] * 32);
        acc4(accA, v0); acc4(accB, v1); acc4(accA, v2); acc4(accB, v3);
    }
    for (; i < e; i += 4) {
        uintx2 v0 = *(const uintx2*)(base + (size_t)col[i] * 32);
        acc4(accA, v0);
    }

    float acc[4];
    #pragma unroll
    for (int j = 0; j < 4; ++j) acc[j] = accA[j] + accB[j];

    #pragma unroll
    for (int j = 0; j < 4; ++j) {
        acc[j] += __shfl_xor(acc[j], 16, 64);
        acc[j] += __shfl_xor(acc[j], 32, 64);
    }
    float s1 = 0.f, s2 = 0.f;
    #pragma unroll
    for (int j = 0; j < 4; ++j) { s1 += acc[j]; s2 += acc[j] * acc[j]; }
    #pragma unroll
    for (int m = 8; m >= 1; m >>= 1) {
        s1 += __shfl_xor(s1, m, 64);
        s2 += __shfl_xor(s2, m, 64);
    }
    const float mean = s1 * (1.0f / 64.0f);
    const float var  = s2 * (1.0f / 64.0f) - mean * mean;
    const float inv  = rsqrtf(var + 1e-5f);

    if (g == 0) {
        floatx4 o;
        o.x = (acc[0] - mean) * inv;
        o.y = (acc[1] - mean) * inv;
        o.z = (acc[2] - mean) * inv;
        o.w = (acc[3] - mean) * inv;
        __builtin_nontemporal_store(o, (floatx4*)(out + (size_t)node * 64 + sl * 4));
    }
}

extern "C" void kernel_launch(void* const* d_in, const int* in_sizes, int n_in,
                              void* d_out, int out_size, void* d_ws, size_t ws_size,
                              hipStream_t stream) {
    const float* feat = (const float*)d_in[0];   // [N,128]
    const float* W0   = (const float*)d_in[1];   // [128,128]
    const float* W1   = (const float*)d_in[2];   // [128,128]
    const float* W2   = (const float*)d_in[3];   // [128,64]
    const int*   ptr  = (const int*)d_in[4];     // [N+1]
    const int*   col  = (const int*)d_in[5];     // [E]
    // d_in[6] = edge_rows, unused (CSR ptr encodes the same segments)

    const int N = in_sizes[4] - 1;               // 50000 (= 3125 * 16)

    unsigned int* xwp = (unsigned int*)d_ws;                 // [N,64] uint, row-major
    unsigned int* hb  = xwp + (size_t)N * 64;                // [N,64] uint, frag order
    unsigned int* fb  = hb + (size_t)N * 64;                 // [N,64] uint, frag order
    unsigned int* WtP = fb + (size_t)N * 64;                 // 3 x frag-ordered W
    float*        out = (float*)d_out;                       // [N,64]

    const int gemmBlocks = (N + 15) / 16;        // 3125 (1 wave each)
    const int nodeBlocks = (N + 3) / 4;          // 12500

    cvt_all<<<gemmBlocks + 48, 256, 0, stream>>>(feat, W0, W1, W2, fb, WtP, gemmBlocks);

    // Layer 0
    gemm_mfma<128><<<gemmBlocks, 64, 0, stream>>>(fb, WtP, xwp, N);
    agg_ln128<<<nodeBlocks, 256, 0, stream>>>(xwp, ptr, col, hb, N);
    // Layer 1
    gemm_mfma<128><<<gemmBlocks, 64, 0, stream>>>(hb, WtP + 128 * 64, xwp, N);
    agg_ln128<<<nodeBlocks, 256, 0, stream>>>(xwp, ptr, col, hb, N);
    // Layer 2 (D_out=64, no ReLU, fp32 out)
    gemm_mfma<64><<<gemmBlocks, 64, 0, stream>>>(hb, WtP + 2 * 128 * 64, xwp, N);
    agg_ln64<<<nodeBlocks, 256, 0, stream>>>(xwp, ptr, col, out, N);
}

// Round 17
// 203.228 us; speedup vs baseline: 1.0245x; 1.0245x over previous
//
#include <hip/hip_runtime.h>
#include <cstddef>

// ---------------------------------------------------------------------------
// GCN forward: 3 x ( h@W bf16 MFMA -> packed-bf16 xw -> CSR segsum+LN(+ReLU) )
// N=50000, E=800000, D: 128 -> 128 -> 128 -> 64.
// R17 = R16 with nt-stores REVERTED to normal stores (R16 regressed +6.4us vs
// R13: nt pushed the read-once hb stream to HBM, starving the consumer gemm's
// L2/L3 hits; the gather table was never under L2 eviction pressure anyway).
// Keeps: frag-ordered feat via LDS transpose, merged cvt_all, pure-frag gemms.
// ---------------------------------------------------------------------------

typedef __attribute__((ext_vector_type(8))) short bf16x8;
typedef __attribute__((ext_vector_type(4))) float floatx4;
typedef __attribute__((ext_vector_type(4))) unsigned int uintx4;
typedef __attribute__((ext_vector_type(2))) unsigned int uintx2;

static __device__ __forceinline__ unsigned int f2bf(float f) {
    union { float f; unsigned int u; } v; v.f = f;
    unsigned int u = v.u;
    u += 0x7fffu + ((u >> 16) & 1u);
    return u >> 16;
}
static __device__ __forceinline__ float bf_lo(unsigned int p) {
    union { unsigned int u; float f; } v; v.u = p << 16; return v.f;
}
static __device__ __forceinline__ float bf_hi(unsigned int p) {
    union { unsigned int u; float f; } v; v.u = p & 0xffff0000u; return v.f;
}
static __device__ __forceinline__ void acc8(float* a, uintx4 v) {
    a[0] += bf_lo(v.x); a[1] += bf_hi(v.x);
    a[2] += bf_lo(v.y); a[3] += bf_hi(v.y);
    a[4] += bf_lo(v.z); a[5] += bf_hi(v.z);
    a[6] += bf_lo(v.w); a[7] += bf_hi(v.w);
}
static __device__ __forceinline__ void acc4(float* a, uintx2 v) {
    a[0] += bf_lo(v.x); a[1] += bf_hi(v.x);
    a[2] += bf_lo(v.y); a[3] += bf_hi(v.y);
}

// ---- one-shot convert: feat -> frag-ordered fb, W0..2 -> frag-ordered WtF --
__global__ __launch_bounds__(256) void cvt_all(const float* __restrict__ feat,
                                               const float* __restrict__ W0,
                                               const float* __restrict__ W1,
                                               const float* __restrict__ W2,
                                               unsigned int* __restrict__ fb,
                                               unsigned int* __restrict__ WtF,
                                               int nTiles) {
    const int b = blockIdx.x;
    if (b < nTiles) {
        __shared__ unsigned int lds[16 * 65];      // stride 65: conflict-free
        const float* src = feat + (size_t)b * 2048;   // 16 rows x 128 floats
        const int i = threadIdx.x;
        float4 fa = *(const float4*)(src + i * 8);
        float4 fv = *(const float4*)(src + i * 8 + 4);
        const int row = i >> 4;                    // 0..15
        const int kk  = (i & 15) * 4;              // uint offset in row
        unsigned int* l = &lds[row * 65 + kk];
        l[0] = (f2bf(fa.y) << 16) | f2bf(fa.x);
        l[1] = (f2bf(fa.w) << 16) | f2bf(fa.z);
        l[2] = (f2bf(fv.y) << 16) | f2bf(fv.x);
        l[3] = (f2bf(fv.w) << 16) | f2bf(fv.z);
        __syncthreads();
        const int lane = i & 63, s = i >> 6;
        const int m = lane & 15, quad = lane >> 4;
        const unsigned int* r = &lds[m * 65 + s * 16 + quad * 4];
        uintx4 v; v.x = r[0]; v.y = r[1]; v.z = r[2]; v.w = r[3];
        *(uintx4*)(fb + (size_t)b * 1024 + i * 4) = v;
    } else {
        const int wb = b - nTiles;
        const int mm = wb >> 4;
        const int slice = wb & 15;
        const float* W = (mm == 0) ? W0 : (mm == 1) ? W1 : W2;
        const int ncols = (mm == 2) ? 64 : 128;
        unsigned int* dst = WtF + mm * 128 * 64;
        const int total = ncols * 64;
        for (int idx = slice * 256 + threadIdx.x; idx < total; idx += 16 * 256) {
            const int j    = idx & 3;
            const int lane = (idx >> 2) & 63;
            const int s    = (idx >> 8) & 3;
            const int t    = idx >> 10;
            const int mcol = lane & 15;
            const int quad = lane >> 4;
            const int n = t * 16 + mcol;
            const int k = s * 32 + quad * 8 + 2 * j;
            unsigned int lo = f2bf(W[(size_t)k * ncols + n]);
            unsigned int hi = f2bf(W[(size_t)(k + 1) * ncols + n]);
            dst[idx] = (hi << 16) | lo;
        }
    }
}

// ---- bf16 MFMA GEMM, 1 wave per block, all operands fragment-ordered -------
template <int NCOLS>
__global__ __launch_bounds__(64) void gemm_mfma(const unsigned int* __restrict__ A,
                                                const unsigned int* __restrict__ Wt,
                                                unsigned int* __restrict__ C,
                                                int M) {
    const int lane = threadIdx.x;
    const int row0 = blockIdx.x * 16;
    const int quad = lane >> 4;
    const int mcol = lane & 15;

    constexpr int NT = NCOLS / 16;
    floatx4 acc[NT];
    #pragma unroll
    for (int t = 0; t < NT; ++t) acc[t] = (floatx4){0.f, 0.f, 0.f, 0.f};

    const unsigned int* afrag = A + (size_t)blockIdx.x * 1024 + lane * 4;
    const unsigned int* bbase = Wt + lane * 4;

    #pragma unroll
    for (int s = 0; s < 4; ++s) {
        uintx4 ap = *(const uintx4*)(afrag + s * 256);
        bf16x8 a = __builtin_bit_cast(bf16x8, ap);
        #pragma unroll
        for (int t = 0; t < NT; ++t) {
            uintx4 bp = *(const uintx4*)(bbase + t * 1024 + s * 256);
            bf16x8 b = __builtin_bit_cast(bf16x8, bp);
            acc[t] = __builtin_amdgcn_mfma_f32_16x16x32_bf16(a, b, acc[t], 0, 0, 0);
        }
    }

    // C/D layout: col = lane&15, row = quad*4 + reg  [m89/m91]; row-major out.
    const int rowStride = NCOLS >> 1;
    #pragma unroll
    for (int t = 0; t < NT; ++t) {
        #pragma unroll
        for (int r = 0; r < 4; ++r) {
            unsigned int mybf = f2bf(acc[t][r]);
            unsigned int pair = __shfl_xor(mybf, 1, 64);
            int orow = row0 + quad * 4 + r;
            if (orow < M && (mcol & 1) == 0) {
                unsigned int packed = (pair << 16) | mybf;
                C[(size_t)orow * rowStride + t * 8 + (mcol >> 1)] = packed;
            }
        }
    }
}

// ---- fused CSR segsum + LN + ReLU, D=128, frag-ordered bf16 out ------------
__global__ __launch_bounds__(256) void agg_ln128(const unsigned int* __restrict__ xw,
                                                 const int* __restrict__ ptr,
                                                 const int* __restrict__ col,
                                                 unsigned int* __restrict__ out,
                                                 int N) {
    const int node = blockIdx.x * 4 + (threadIdx.x >> 6);
    if (node >= N) return;
    const int lane = threadIdx.x & 63;
    const int g  = lane >> 4;     // 0..3 edge group
    const int sl = lane & 15;     // 0..15 sublane (owns 8 features)
    const int s = ptr[node];
    const int e = ptr[node + 1];

    float accA[8] = {}, accB[8] = {};
    const unsigned int* base = xw + sl * 4;
    int i = s + g;
    for (; i + 12 < e; i += 16) {
        uintx4 v0 = *(const uintx4*)(base + (size_t)col[i]      * 64);
        uintx4 v1 = *(const uintx4*)(base + (size_t)col[i + 4]  * 64);
        uintx4 v2 = *(const uintx4*)(base + (size_t)col[i + 8]  * 64);
        uintx4 v3 = *(const uintx4*)(base + (size_t)col[i + 12] * 64);
        acc8(accA, v0); acc8(accB, v1); acc8(accA, v2); acc8(accB, v3);
    }
    for (; i < e; i += 4) {
        uintx4 v0 = *(const uintx4*)(base + (size_t)col[i] * 64);
        acc8(accA, v0);
    }

    float acc[8];
    #pragma unroll
    for (int j = 0; j < 8; ++j) acc[j] = accA[j] + accB[j];

    #pragma unroll
    for (int j = 0; j < 8; ++j) {
        acc[j] += __shfl_xor(acc[j], 16, 64);
        acc[j] += __shfl_xor(acc[j], 32, 64);
    }
    float s1 = 0.f, s2 = 0.f;
    #pragma unroll
    for (int j = 0; j < 8; ++j) { s1 += acc[j]; s2 += acc[j] * acc[j]; }
    #pragma unroll
    for (int m = 8; m >= 1; m >>= 1) {
        s1 += __shfl_xor(s1, m, 64);
        s2 += __shfl_xor(s2, m, 64);
    }
    const float mean = s1 * (1.0f / 128.0f);
    const float var  = s2 * (1.0f / 128.0f) - mean * mean;
    const float inv  = rsqrtf(var + 1e-5f);

    if (g == 0) {
        float o[8];
        #pragma unroll
        for (int j = 0; j < 8; ++j)
            o[j] = fmaxf((acc[j] - mean) * inv, 0.f);
        uintx4 p;
        p.x = (f2bf(o[1]) << 16) | f2bf(o[0]);
        p.y = (f2bf(o[3]) << 16) | f2bf(o[2]);
        p.z = (f2bf(o[5]) << 16) | f2bf(o[4]);
        p.w = (f2bf(o[7]) << 16) | f2bf(o[6]);
        const int tile = node >> 4, m = node & 15;
        *(uintx4*)(out + (size_t)tile * 1024 + (sl >> 2) * 256 + (sl & 3) * 64 + m * 4) = p;
    }
}

// ---- fused CSR segsum + LN, D=64, fp32 out, no ReLU (final layer) ----------
__global__ __launch_bounds__(256) void agg_ln64(const unsigned int* __restrict__ xw,
                                                const int* __restrict__ ptr,
                                                const int* __restrict__ col,
                                                float* __restrict__ out, int N) {
    const int node = blockIdx.x * 4 + (threadIdx.x >> 6);
    if (node >= N) return;
    const int lane = threadIdx.x & 63;
    const int g  = lane >> 4;     // 0..3 edge group
    const int sl = lane & 15;     // 0..15 sublane (owns 4 features)
    const int s = ptr[node];
    const int e = ptr[node + 1];

    float accA[4] = {}, accB[4] = {};
    const unsigned int* base = xw + sl * 2;
    int i = s + g;
    for (; i + 12 < e; i += 16) {
        uintx2 v0 = *(const uintx2*)(base + (size_t)col[i]      * 32);
        uintx2 v1 = *(const uintx2*)(base + (size_t)col[i + 4]  * 32);
        uintx2 v2 = *(const uintx2*)(base + (size_t)col[i + 8]  * 32);
        uintx2 v3 = *(const uintx2*)(base + (size_t)col[i + 12] * 32);
        acc4(accA, v0); acc4(accB, v1); acc4(accA, v2); acc4(accB, v3);
    }
    for (; i < e; i += 4) {
        uintx2 v0 = *(const uintx2*)(base + (size_t)col[i] * 32);
        acc4(accA, v0);
    }

    float acc[4];
    #pragma unroll
    for (int j = 0; j < 4; ++j) acc[j] = accA[j] + accB[j];

    #pragma unroll
    for (int j = 0; j < 4; ++j) {
        acc[j] += __shfl_xor(acc[j], 16, 64);
        acc[j] += __shfl_xor(acc[j], 32, 64);
    }
    float s1 = 0.f, s2 = 0.f;
    #pragma unroll
    for (int j = 0; j < 4; ++j) { s1 += acc[j]; s2 += acc[j] * acc[j]; }
    #pragma unroll
    for (int m = 8; m >= 1; m >>= 1) {
        s1 += __shfl_xor(s1, m, 64);
        s2 += __shfl_xor(s2, m, 64);
    }
    const float mean = s1 * (1.0f / 64.0f);
    const float var  = s2 * (1.0f / 64.0f) - mean * mean;
    const float inv  = rsqrtf(var + 1e-5f);

    if (g == 0) {
        float4 o;
        o.x = (acc[0] - mean) * inv;
        o.y = (acc[1] - mean) * inv;
        o.z = (acc[2] - mean) * inv;
        o.w = (acc[3] - mean) * inv;
        *(float4*)(out + (size_t)node * 64 + sl * 4) = o;
    }
}

extern "C" void kernel_launch(void* const* d_in, const int* in_sizes, int n_in,
                              void* d_out, int out_size, void* d_ws, size_t ws_size,
                              hipStream_t stream) {
    const float* feat = (const float*)d_in[0];   // [N,128]
    const float* W0   = (const float*)d_in[1];   // [128,128]
    const float* W1   = (const float*)d_in[2];   // [128,128]
    const float* W2   = (const float*)d_in[3];   // [128,64]
    const int*   ptr  = (const int*)d_in[4];     // [N+1]
    const int*   col  = (const int*)d_in[5];     // [E]
    // d_in[6] = edge_rows, unused (CSR ptr encodes the same segments)

    const int N = in_sizes[4] - 1;               // 50000 (= 3125 * 16)

    unsigned int* xwp = (unsigned int*)d_ws;                 // [N,64] uint, row-major
    unsigned int* hb  = xwp + (size_t)N * 64;                // [N,64] uint, frag order
    unsigned int* fb  = hb + (size_t)N * 64;                 // [N,64] uint, frag order
    unsigned int* WtP = fb + (size_t)N * 64;                 // 3 x frag-ordered W
    float*        out = (float*)d_out;                       // [N,64]

    const int gemmBlocks = (N + 15) / 16;        // 3125 (1 wave each)
    const int nodeBlocks = (N + 3) / 4;          // 12500

    cvt_all<<<gemmBlocks + 48, 256, 0, stream>>>(feat, W0, W1, W2, fb, WtP, gemmBlocks);

    // Layer 0
    gemm_mfma<128><<<gemmBlocks, 64, 0, stream>>>(fb, WtP, xwp, N);
    agg_ln128<<<nodeBlocks, 256, 0, stream>>>(xwp, ptr, col, hb, N);
    // Layer 1
    gemm_mfma<128><<<gemmBlocks, 64, 0, stream>>>(hb, WtP + 128 * 64, xwp, N);
    agg_ln128<<<nodeBlocks, 256, 0, stream>>>(xwp, ptr, col, hb, N);
    // Layer 2 (D_out=64, no ReLU, fp32 out)
    gemm_mfma<64><<<gemmBlocks, 64, 0, stream>>>(hb, WtP + 2 * 128 * 64, xwp, N);
    agg_ln64<<<nodeBlocks, 256, 0, stream>>>(xwp, ptr, col, out, N);
}